// Round 1
// 110.987 us; speedup vs baseline: 1.0733x; 1.0733x over previous
//
#include <hip/hip_runtime.h>
#include <stdint.h>

#define NBOX 8000
#define NPAD 8192

// ---- workspace layout (bytes) ----
#define ECNT_OFF 0                           // u32 edge count (zeroed by sort_decode)
#define ALIVE_OFF 0x1000                     // 128 x u64 alive bitmap (nms -> out)
#define SB(i)    (0x10000 + (size_t)(i) * 0x8000)
// sorted-by-rank arrays (float[8192] each):
// 0 bx, 1 by, 2 bw, 3 bh, 4 conf, 5 cls, 6 x1, 7 y1, 8 x2, 9 y2, 10 area
#define EDGE_OFF (size_t)0x200000            // u32 edges (i<<13|j); max 134MB < ws

__device__ __forceinline__ float sigmoidf_(float x) {
    return 1.0f / (1.0f + expf(-x));
}

// ---------------- fused decode + rank + scatter-to-sorted ----------------
// Block b owns source boxes [b*32, b*32+32)  (256 blocks -> all 256 CUs).
// Phase 1: 512 threads materialize ALL 8192 keys into LDS once. ONE barrier.
// Phase 2: ballot-rank. Each wave loads its 1024-key segment into 16 u64
//          regs/lane (17 LDS reads total vs 1024 before). For each of the
//          block's 32 source keys: broadcast via readlane (SGPR), compare
//          all 64 reg-keys per chunk with v_cmp_gt_u64, count via
//          __ballot+__popcll (scalar pipe). LDS pipe is no longer the
//          bottleneck; VALU cost ~1.3k cy/wave.
// Phase 3: wave 0 (lanes 0..31) sums the 8 partials per row, fully decodes
//          its 32 CONSECUTIVE boxes (coalesced loads; only rank-indexed
//          stores scatter) and writes the sorted arrays directly.
// Validity downstream = sconf[r] > 0.5 (sorted => equivalent to r < V).
__global__ __launch_bounds__(512) void sort_decode_kernel(const float* __restrict__ x,
                                                          const float* __restrict__ anchors,
                                                          unsigned char* __restrict__ ws) {
    __shared__ unsigned long long keys[NPAD];    // 64 KB
    __shared__ int partial[256];                 // 8 waves x 32 rows
    int tid  = threadIdx.x;
    int lane = tid & 63;
    int wv   = tid >> 6;                         // wave 0..7
    int b    = blockIdx.x;                       // 256 blocks

    if (b == 0 && tid == 0) *(unsigned int*)(ws + ECNT_OFF) = 0u;   // for mask_kernel

    // ---- phase 1: all keys -> LDS (16 coalesced loads/thread) ----
    for (int t = tid; t < NPAD; t += 512) {
        unsigned long long k;
        if (t < NBOX) {
            int a = t / 1600, pos = t - a * 1600;
            float c = sigmoidf_(x[a * 40000 + 4 * 1600 + pos]);
            k = ((unsigned long long)__float_as_uint(c) << 32) | (unsigned long long)(8191 - t);
        } else {
            k = (unsigned long long)(8191 - t);  // pads sort last (conf bits = 0)
        }
        keys[t] = k;
    }
    __syncthreads();

    // ---- phase 2: ballot-rank; wave wv vs segment wv ----
    unsigned long long kj[16];
    #pragma unroll
    for (int c = 0; c < 16; ++c) kj[c] = keys[(wv << 10) + (c << 6) + lane];
    // lanes 0..63 hold keys b*32 .. b*32+63; readlane ii in [0,32) picks the
    // block's 32 source keys.
    unsigned long long ki = keys[(b << 5) + lane];

    int vout = 0;                                // lane L ends with partial for row L
    for (int ii = 0; ii < 32; ++ii) {
        unsigned int klo = (unsigned int)__builtin_amdgcn_readlane((int)(unsigned int)ki, ii);
        unsigned int khi = (unsigned int)__builtin_amdgcn_readlane((int)(unsigned int)(ki >> 32), ii);
        unsigned long long kib = ((unsigned long long)khi << 32) | (unsigned long long)klo;
        int c = 0;
        #pragma unroll
        for (int ch = 0; ch < 16; ++ch)
            c += __popcll(__ballot(kj[ch] > kib));
        vout = (lane == ii) ? c : vout;
    }
    if (lane < 32) partial[(wv << 5) + lane] = vout;
    __syncthreads();

    // ---- phase 3: wave 0 lanes 0..31 sum partials, decode, scatter-write ----
    if (wv == 0 && lane < 32) {
        int r = 0;
        #pragma unroll
        for (int s = 0; s < 8; ++s) r += partial[(s << 5) + lane];

        int i = (b << 5) + lane;                 // source box owned by this lane
        float bx = 0.f, by = 0.f, bw = 0.f, bh = 0.f, conf = 0.f, cls = -1.0f;
        if (i < NBOX) {                          // full decode (coalesced channel loads)
            int a = i / 1600, pos = i - a * 1600;
            int gy = pos / 40, gx = pos - gy * 40;
            const float* p = x + (size_t)a * 40000 + pos;
            float tx = sigmoidf_(p[0]);
            float ty = sigmoidf_(p[1600]);
            float tw = p[2 * 1600];
            float th = p[3 * 1600];
            conf = sigmoidf_(p[4 * 1600]);
            float best = -1.0f; int bi = 0;
            #pragma unroll
            for (int c = 0; c < 20; ++c) {       // first-max wins, matches jnp.argmax
                float v = sigmoidf_(p[(5 + c) * 1600]);
                if (v > best) { best = v; bi = c; }
            }
            float aw = anchors[a * 2 + 0];
            float ah = anchors[a * 2 + 1];
            bx = (tx + (float)gx) * 8.0f;
            by = (ty + (float)gy) * 8.0f;
            bw = expf(tw) * aw * 8.0f;
            bh = expf(th) * ah * 8.0f;
            cls = (float)bi;
        }
        {
        #pragma clang fp contract(off)
            float x1 = bx - bw / 2.0f, y1 = by - bh / 2.0f;
            float x2 = bx + bw / 2.0f, y2 = by + bh / 2.0f;
            float ar = fabsf((x2 - x1) * (y2 - y1));   // ref: recomputed from corners
            ((float*)(ws + SB(0)))[r]  = bx;  ((float*)(ws + SB(1)))[r]  = by;
            ((float*)(ws + SB(2)))[r]  = bw;  ((float*)(ws + SB(3)))[r]  = bh;
            ((float*)(ws + SB(4)))[r]  = conf; ((float*)(ws + SB(5)))[r] = cls;
            ((float*)(ws + SB(6)))[r]  = x1;  ((float*)(ws + SB(7)))[r]  = y1;
            ((float*)(ws + SB(8)))[r]  = x2;  ((float*)(ws + SB(9)))[r]  = y2;
            ((float*)(ws + SB(10)))[r] = ar;
        }
    }
}

// ---------------- suppression edges: (i<<13|j) for j>i, same cls, IoU>=0.5 ----------------
// Validity via sorted conf (> 0.5); block-uniform early exits read sconf at
// tile heads (sorted descending). Wave-aggregated edge compaction.
__global__ __launch_bounds__(256) void mask_kernel(unsigned char* __restrict__ ws) {
#pragma clang fp contract(off)
    const float* sconf = (const float*)(ws + SB(4));
    int i0 = blockIdx.y * 256;
    int w  = blockIdx.x;
    int j0 = w * 64;
    if (sconf[i0] <= 0.5f) return;                 // whole i-tile invalid (sorted)
    if (sconf[j0] <= 0.5f) return;                 // whole j-word invalid
    if (j0 + 64 <= i0) return;                     // strictly sub-diagonal: empty
    int tid  = threadIdx.x;
    int lane = tid & 63;
    int i    = i0 + tid;

    const float* sx1 = (const float*)(ws + SB(6));
    const float* sy1 = (const float*)(ws + SB(7));
    const float* sx2 = (const float*)(ws + SB(8));
    const float* sy2 = (const float*)(ws + SB(9));
    const float* sar = (const float*)(ws + SB(10));
    const float* scl = (const float*)(ws + SB(5));

    __shared__ float cx1[64], cy1[64], cx2[64], cy2[64], car[64], ccl[64], ccf[64];
    if (tid < 64) {
        int j = j0 + tid;
        cx1[tid] = sx1[j]; cy1[tid] = sy1[j];
        cx2[tid] = sx2[j]; cy2[tid] = sy2[j];
        car[tid] = sar[j]; ccl[tid] = scl[j]; ccf[tid] = sconf[j];
    }
    __syncthreads();

    unsigned long long word = 0;
    if (sconf[i] > 0.5f && j0 + 64 > i + 1) {      // row i valid
        float x1i = sx1[i], y1i = sy1[i], x2i = sx2[i], y2i = sy2[i];
        float ai = sar[i], ci = scl[i];
        for (int jj = 0; jj < 64; ++jj) {
            int j = j0 + jj;
            if (j <= i) continue;
            if (ccf[jj] <= 0.5f) continue;         // col j invalid (== j >= V)
            if (ccl[jj] != ci) continue;
            float iw = fminf(x2i, cx2[jj]) - fmaxf(x1i, cx1[jj]);
            iw = fmaxf(iw, 0.0f);
            float ih = fminf(y2i, cy2[jj]) - fmaxf(y1i, cy1[jj]);
            ih = fmaxf(ih, 0.0f);
            float inter = iw * ih;
            float denom = ai + car[jj] - inter + 1e-6f;   // ((ai+aj)-inter)+eps, L-to-R
            if (inter / denom >= 0.5f) word |= (1ull << jj);
        }
    }

    // wave-aggregated edge emission (all 64 lanes participate)
    int pc = __popcll(word);
    int scan = pc;
    #pragma unroll
    for (int d = 1; d < 64; d <<= 1) {
        int t = __shfl_up(scan, d, 64);
        if (lane >= d) scan += t;
    }
    int total = __shfl(scan, 63, 64);
    if (total > 0) {
        unsigned int base = 0;
        if (lane == 63)
            base = atomicAdd((unsigned int*)(ws + ECNT_OFF), (unsigned int)total);
        base = (unsigned int)__shfl((int)base, 63, 64);
        unsigned int off = base + (unsigned int)(scan - pc);   // exclusive prefix
        unsigned int* edges = (unsigned int*)(ws + EDGE_OFF);
        unsigned long long t = word;
        while (t) {
            int bit = __builtin_ctzll(t);
            t &= t - 1ull;
            edges[off++] = ((unsigned int)i << 13) | (unsigned int)(j0 + bit);
        }
    }
}

// ---------------- NMS via Jacobi fixed point ----------------
// Greedy NMS == unique fixed point of a[j] = valid[j] & ~OR_{i<j, edge} a[i].
// Single block, LDS bitmaps, exact change-detection. Edges staged in LDS
// when they fit (they do on this data) so each pass reads LDS, not L2.
// Writes the alive bitmap to ws for the multi-block output kernel.
#define ELDS 32768
__global__ __launch_bounds__(1024, 1) void nms_kernel(unsigned char* __restrict__ ws) {
    int tid  = threadIdx.x;
    int lane = tid & 63;
    unsigned int E = *(const unsigned int*)(ws + ECNT_OFF);
    const unsigned int* edges = (const unsigned int*)(ws + EDGE_OFF);
    const float* sconf = (const float*)(ws + SB(4));

    __shared__ unsigned long long valid[128], alive[128], supp[128];
    __shared__ int flag;
    __shared__ unsigned int eld[ELDS];             // 128 KB

    for (int c = tid >> 6; c < 128; c += 16) {     // 16 waves, 8 chunks each
        unsigned long long m = __ballot(sconf[(c << 6) + lane] > 0.5f);
        if (lane == 0) valid[c] = m;
    }
    bool uselds = (E <= (unsigned int)ELDS);
    if (uselds)
        for (unsigned int e = tid; e < E; e += 1024) eld[e] = edges[e];
    __syncthreads();
    if (tid < 128) alive[tid] = valid[tid];
    __syncthreads();

    for (;;) {
        if (tid < 128) supp[tid] = 0ull;
        __syncthreads();
        if (uselds) {
            for (unsigned int e = tid; e < E; e += 1024) {
                unsigned int u = eld[e];
                unsigned int i = u >> 13, j = u & 8191u;
                if ((alive[i >> 6] >> (i & 63)) & 1ull)
                    atomicOr(&supp[j >> 6], 1ull << (j & 63));
            }
        } else {
            for (unsigned int e = tid; e < E; e += 1024) {
                unsigned int u = edges[e];
                unsigned int i = u >> 13, j = u & 8191u;
                if ((alive[i >> 6] >> (i & 63)) & 1ull)
                    atomicOr(&supp[j >> 6], 1ull << (j & 63));
            }
        }
        if (tid == 0) flag = 0;
        __syncthreads();
        if (tid < 128) {
            unsigned long long na = valid[tid] & ~supp[tid];
            if (na != alive[tid]) { alive[tid] = na; flag = 1; }
        }
        __syncthreads();
        if (!flag) break;
    }

    if (tid < 128) ((unsigned long long*)(ws + ALIVE_OFF))[tid] = alive[tid];
}

// ---------------- output: kept ranks -> sorted box values, else zeros ----------------
// 32 blocks; LDS-transpose staging so all global stores are fully coalesced.
__global__ __launch_bounds__(256) void out_kernel(const unsigned char* __restrict__ ws,
                                                  float* __restrict__ out) {
    __shared__ float o[256 * 6];
    int tid = threadIdx.x;
    int r0  = blockIdx.x << 8;
    int r   = r0 + tid;
    const unsigned long long* alive = (const unsigned long long*)(ws + ALIVE_OFF);

    float v0 = 0.f, v1 = 0.f, v2 = 0.f, v3 = 0.f, v4 = 0.f, v5 = 0.f;
    if (r < NBOX && ((alive[r >> 6] >> (r & 63)) & 1ull)) {
        v0 = ((const float*)(ws + SB(0)))[r];
        v1 = ((const float*)(ws + SB(1)))[r];
        v2 = ((const float*)(ws + SB(2)))[r];
        v3 = ((const float*)(ws + SB(3)))[r];
        v4 = ((const float*)(ws + SB(4)))[r];
        v5 = ((const float*)(ws + SB(5)))[r];
    }
    o[tid * 6 + 0] = v0; o[tid * 6 + 1] = v1; o[tid * 6 + 2] = v2;
    o[tid * 6 + 3] = v3; o[tid * 6 + 4] = v4; o[tid * 6 + 5] = v5;
    __syncthreads();

    int base = r0 * 6;
    for (int t = tid; t < 256 * 6; t += 256) {
        int idx = base + t;
        if (idx < NBOX * 6) out[idx] = o[t];
    }
}

extern "C" void kernel_launch(void* const* d_in, const int* in_sizes, int n_in,
                              void* d_out, int out_size, void* d_ws, size_t ws_size,
                              hipStream_t stream) {
    const float* x       = (const float*)d_in[0];
    const float* anchors = (const float*)d_in[1];
    float* out           = (float*)d_out;
    unsigned char* ws    = (unsigned char*)d_ws;

    sort_decode_kernel<<<NPAD / 32, 512, 0, stream>>>(x, anchors, ws);
    dim3 mgrid(128, NPAD / 256);
    mask_kernel<<<mgrid, 256, 0, stream>>>(ws);
    nms_kernel<<<1, 1024, 0, stream>>>(ws);
    out_kernel<<<32, 256, 0, stream>>>(ws, out);
}